// Round 11
// baseline (450.210 us; speedup 1.0000x reference)
//
#include <hip/hip_runtime.h>

#define BB 1024
#define TT 512
#define KK 64
#define NEGV -10000.0f

typedef _Float16 h2 __attribute__((ext_vector_type(2)));

#if defined(__has_builtin)
#if __has_builtin(__builtin_amdgcn_fdot2)
#define HAVE_FDOT2 1
#endif
#if __has_builtin(__builtin_amdgcn_readlane)
#define HAVE_READLANE 1
#endif
#endif

static __device__ __forceinline__ float dot2_acc(h2 a, h2 b, float c) {
#ifdef HAVE_FDOT2
    return __builtin_amdgcn_fdot2(a, b, c, false);
#else
    return fmaf((float)a.x, (float)b.x, fmaf((float)a.y, (float)b.y, c));
#endif
}

static __device__ __forceinline__ h2 bc_h2(float f) {
    return __builtin_bit_cast(h2, f);
}

// wave-uniform lane-8 read: v_readlane -> SGPR (no DS op, unlike __shfl)
static __device__ __forceinline__ float lane8(float x) {
#ifdef HAVE_READLANE
    return __builtin_bit_cast(
        float, __builtin_amdgcn_readlane(__builtin_bit_cast(int, x), 8));
#else
    return __shfl(x, 8);
#endif
}

// ---------------------------------------------------------------------------
// crf_kernel: ONE wave per batch, F and V merged in one instruction stream
// (independent chains hide each other's DS/VALU latency). Structure = R6
// (best measured: 350.8 us), plus two DS-pressure trims:
//   * ref normalizer via v_readlane (was ds_bpermute)
//   * backpointers packed 4 steps per u32 -> 1 ds_write_b32 per 4 steps
// The deferred argmax epilogue (operand re-reads issued at step t, consumed
// at t+1) and all numerics are bitwise-identical to R6 (absmax 0.0).
// ---------------------------------------------------------------------------
__global__ __launch_bounds__(64, 1) void crf_kernel(const float* __restrict__ feats,
                                                    const int* __restrict__ tags,
                                                    const float* __restrict__ trans,
                                                    float* __restrict__ out) {
    __shared__ unsigned int bp4[TT / 4][KK];        // 32 KB packed backpointers
    __shared__ __align__(16) float wa_buf[KK];      // viterbi alpha broadcast
    __shared__ __align__(16) _Float16 ea_buf[KK];   // exp(alpha - ref), f16

    const int b = blockIdx.x;
    const int lane = threadIdx.x;

    // ---- gold score (one-time, lane-parallel gather) ----
    const int* tg = tags + (size_t)b * TT;
    float gold = 0.f;
#pragma unroll
    for (int i = 0; i < TT / 64; ++i) {
        int t = lane + i * 64;
        int nxt = tg[t];
        int prv = t ? tg[t - 1] : 0;
        gold += trans[nxt * KK + prv] + feats[((size_t)b * TT + t) * KK + nxt];
    }
    if (lane == 0) gold += trans[(KK - 1) * KK + tg[TT - 1]];  // STOP term
#pragma unroll
    for (int d = 1; d < 64; d <<= 1) gold += __shfl_xor(gold, d);

    // ---- per-lane transition row (lane = next state) ----
    float tr[KK];
    h2 Er_pk[KK / 2];   // exp(tr) packed f16 pairs for the forward dot2
    {
        const float4* trow = reinterpret_cast<const float4*>(trans + lane * KK);
#pragma unroll
        for (int i = 0; i < KK / 4; ++i) {
            float4 v = trow[i];
            tr[4 * i + 0] = v.x; tr[4 * i + 1] = v.y;
            tr[4 * i + 2] = v.z; tr[4 * i + 3] = v.w;
            h2 lo, hi;
            lo.x = (_Float16)__expf(v.x); lo.y = (_Float16)__expf(v.y);
            hi.x = (_Float16)__expf(v.z); hi.y = (_Float16)__expf(v.w);
            Er_pk[2 * i] = lo;
            Er_pk[2 * i + 1] = hi;
        }
    }
    const float t63 = trans[(KK - 1) * KK + lane];  // trans[STOP][lane]

    float a = (lane == 0) ? 0.f : NEGV;   // forward alpha (log domain)
    float w = a;                          // viterbi alpha (lane = state)
    wa_buf[lane] = w;
    // pipelined wave-uniform normalizer: refUse(t) = readlane(a_{t-2}, 8) + 5
    float refUse = 0.f, refMid = 6.f, refNew = 12.f;

    // feats prefetch ring, depth 4
    const float* fbp = feats + (size_t)b * TT * KK + lane;
    float f0 = fbp[0 * KK];
    float f1 = fbp[1 * KK];
    float f2 = fbp[2 * KK];
    float f3 = fbp[3 * KK];
    const float* fp = fbp + 4 * KK;

    // pending (deferred) epilogue state for step t-1
    float4 p_wa0 = {}, p_wa1 = {}, p_tg0 = {}, p_tg1 = {};
    float p_m = 0.f;
    int p_base = 0;
    unsigned int bpacc = 0;   // 4 packed bp bytes

    for (int t = 0; t < TT; ++t) {
        // ---- finish step t-1: argmax compare + packed bp store ----
        if (t) {
            int bpv = p_base;
            float vv;
            vv = p_wa1.w + p_tg1.w; if (vv == p_m) bpv = p_base + 7;
            vv = p_wa1.z + p_tg1.z; if (vv == p_m) bpv = p_base + 6;
            vv = p_wa1.y + p_tg1.y; if (vv == p_m) bpv = p_base + 5;
            vv = p_wa1.x + p_tg1.x; if (vv == p_m) bpv = p_base + 4;
            vv = p_wa0.w + p_tg0.w; if (vv == p_m) bpv = p_base + 3;
            vv = p_wa0.z + p_tg0.z; if (vv == p_m) bpv = p_base + 2;
            vv = p_wa0.y + p_tg0.y; if (vv == p_m) bpv = p_base + 1;
            vv = p_wa0.x + p_tg0.x; if (vv == p_m) bpv = p_base + 0;
            const int s = t - 1;
            bpacc |= (unsigned int)bpv << ((s & 3) * 8);
            if ((s & 3) == 3) {          // one b32 write per 4 steps
                bp4[s >> 2][lane] = bpacc;
                bpacc = 0;
            }
        }

        const float f_cur = f0;
        f0 = f1; f1 = f2; f2 = f3;
        f3 = *fp;                       // row min(t+4, TT-1)
        if (t + 5 < TT) fp += KK;

        // ======== forward: publish normalized exp(alpha), f16 ========
        float x = fminf(a - refUse, 11.0f);     // e^11 < f16 max
        ea_buf[lane] = (_Float16)__expf(x);
        // single-wave block: in-order DS pipe, no barrier needed

        // ======== viterbi: candidates + group maxima (no c[] kept) ========
        float gm[8];
        const float4* wb = reinterpret_cast<const float4*>(wa_buf);
#pragma unroll
        for (int g = 0; g < 8; ++g) {
            float4 wA = wb[2 * g];
            float4 wB = wb[2 * g + 1];
            float c0 = wA.x + tr[8 * g + 0];
            float c1 = wA.y + tr[8 * g + 1];
            float c2 = wA.z + tr[8 * g + 2];
            float c3 = wA.w + tr[8 * g + 3];
            float c4 = wB.x + tr[8 * g + 4];
            float c5 = wB.y + tr[8 * g + 5];
            float c6 = wB.z + tr[8 * g + 6];
            float c7 = wB.w + tr[8 * g + 7];
            gm[g] = fmaxf(fmaxf(fmaxf(c0, c1), fmaxf(c2, c3)),
                          fmaxf(fmaxf(c4, c5), fmaxf(c6, c7)));
        }

        // ======== forward: dot-products over the broadcast ========
        const float4* eb = reinterpret_cast<const float4*>(ea_buf);
        float s0 = 0.f, s1 = 0.f, s2 = 0.f, s3 = 0.f;
        float s4 = 0.f, s5 = 0.f, s6 = 0.f, s7 = 0.f;
#pragma unroll
        for (int q = 0; q < 8; ++q) {
            float4 e4 = eb[q];
            float acc = 0.f;
            acc = dot2_acc(bc_h2(e4.x), Er_pk[4 * q + 0], acc);
            acc = dot2_acc(bc_h2(e4.y), Er_pk[4 * q + 1], acc);
            acc = dot2_acc(bc_h2(e4.z), Er_pk[4 * q + 2], acc);
            acc = dot2_acc(bc_h2(e4.w), Er_pk[4 * q + 3], acc);
            switch (q) {   // 8 independent chains
                case 0: s0 = acc; break; case 1: s1 = acc; break;
                case 2: s2 = acc; break; case 3: s3 = acc; break;
                case 4: s4 = acc; break; case 5: s5 = acc; break;
                case 6: s6 = acc; break; case 7: s7 = acc; break;
            }
        }
        float s = ((s0 + s1) + (s2 + s3)) + ((s4 + s5) + (s6 + s7));
        float a_new = __logf(s) + refUse + f_cur;
        refUse = refMid;
        refMid = refNew;
        refNew = lane8(a_new) + 5.0f;   // v_readlane: no DS op; used 2 iters on
        a = a_new;

        // ======== viterbi: max, group select, issue deferred loads ========
        float m = fmaxf(fmaxf(fmaxf(gm[0], gm[1]), fmaxf(gm[2], gm[3])),
                        fmaxf(fmaxf(gm[4], gm[5]), fmaxf(gm[6], gm[7])));
        int g = 0;
#pragma unroll
        for (int j = 7; j >= 0; --j)   // descending: smallest matching group
            if (gm[j] == m) g = j;
        const int base = g * 8;

        // re-reads consumed NEXT iteration; wa reads BEFORE the write (old vals)
        const float4* wam = reinterpret_cast<const float4*>(wa_buf + base);
        p_wa0 = wam[0];
        p_wa1 = wam[1];
        wa_buf[lane] = m + f_cur;           // in-order DS pipe: reads saw old
        const float4* trg = reinterpret_cast<const float4*>(trans + lane * KK + base);
        p_tg0 = trg[0];
        p_tg1 = trg[1];                     // L1/L2-resident, full-step cover
        p_m = m;
        p_base = base;
        w = m + f_cur;
    }
    // finish last step's bp (s = TT-1, (s&3)==3 -> writes the final word)
    {
        int bpv = p_base;
        float vv;
        vv = p_wa1.w + p_tg1.w; if (vv == p_m) bpv = p_base + 7;
        vv = p_wa1.z + p_tg1.z; if (vv == p_m) bpv = p_base + 6;
        vv = p_wa1.y + p_tg1.y; if (vv == p_m) bpv = p_base + 5;
        vv = p_wa1.x + p_tg1.x; if (vv == p_m) bpv = p_base + 4;
        vv = p_wa0.w + p_tg0.w; if (vv == p_m) bpv = p_base + 3;
        vv = p_wa0.z + p_tg0.z; if (vv == p_m) bpv = p_base + 2;
        vv = p_wa0.y + p_tg0.y; if (vv == p_m) bpv = p_base + 1;
        vv = p_wa0.x + p_tg0.x; if (vv == p_m) bpv = p_base + 0;
        bpacc |= (unsigned int)bpv << (((TT - 1) & 3) * 8);
        bp4[(TT - 1) >> 2][lane] = bpacc;
    }

    // ---- forward score: exact logsumexp(alpha_T + trans[STOP][:]) ----
    float v = a + t63;
    float mm = v;
#pragma unroll
    for (int d = 32; d; d >>= 1) mm = fmaxf(mm, __shfl_xor(mm, d));
    float es = __expf(v - mm);
#pragma unroll
    for (int d = 32; d; d >>= 1) es += __shfl_xor(es, d);
    float fscore = mm + __logf(es);

    // ---- viterbi terminal: max + first-index argmax (exact) ----
    float tv = w + t63;
    float bvv = tv;
    int bidx = lane;
#pragma unroll
    for (int d = 1; d < 64; d <<= 1) {
        float ov = __shfl_xor(bvv, d);
        int oi = __shfl_xor(bidx, d);
        bool take = (ov > bvv) || (ov == bvv && oi < bidx);
        bvv = take ? ov : bvv;
        bidx = take ? oi : bidx;
    }

    if (lane == 0) {
        out[b] = fscore - gold;
        out[BB + b] = bvv;
    }

    // ---- backtrace: packed LDS row loads + dynamic-shfl chain ----
    float* outp = out + 2 * BB + (size_t)b * TT;
    int cur = bidx;                 // wave-uniform
    float my = 0.f;                 // latched path values (lane = t & 63)
    for (int tb = TT - 16; tb >= 0; tb -= 16) {
        unsigned int rw[4];
#pragma unroll
        for (int j4 = 0; j4 < 4; ++j4) rw[j4] = bp4[(tb >> 2) + j4][lane];
#pragma unroll
        for (int j = 15; j >= 0; --j) {
            my = (lane == ((tb + j) & 63)) ? (float)cur : my;
            int byte = (int)((rw[j >> 2] >> ((j & 3) * 8)) & 255u);
            cur = __shfl(byte, cur);
        }
        if ((tb & 63) == 0) outp[tb + lane] = my;   // coalesced 64-wide store
    }
}

extern "C" void kernel_launch(void* const* d_in, const int* in_sizes, int n_in,
                              void* d_out, int out_size, void* d_ws, size_t ws_size,
                              hipStream_t stream) {
    const float* feats = (const float*)d_in[0];
    const int* tags = (const int*)d_in[1];
    const float* trans = (const float*)d_in[2];
    float* out = (float*)d_out;

    crf_kernel<<<BB, 64, 0, stream>>>(feats, tags, trans, out);
}

// Round 12
// 351.446 us; speedup vs baseline: 1.2810x; 1.2810x over previous
//
#include <hip/hip_runtime.h>

#define BB 1024
#define TT 512
#define KK 64
#define NEGV -10000.0f

typedef _Float16 h2 __attribute__((ext_vector_type(2)));

#if defined(__has_builtin)
#if __has_builtin(__builtin_amdgcn_fdot2)
#define HAVE_FDOT2 1
#endif
#endif

static __device__ __forceinline__ float dot2_acc(h2 a, h2 b, float c) {
#ifdef HAVE_FDOT2
    return __builtin_amdgcn_fdot2(a, b, c, false);
#else
    return fmaf((float)a.x, (float)b.x, fmaf((float)a.y, (float)b.y, c));
#endif
}

static __device__ __forceinline__ h2 bc_h2(float f) {
    return __builtin_bit_cast(h2, f);
}

// ---------------------------------------------------------------------------
// crf_kernel (R6 structure -- best measured: 350.8 us headline, 385 profiled).
// ONE wave per batch, forward and Viterbi recurrences MERGED in one
// instruction stream: the two chains are independent within a step, so each
// hides the other's DS/VALU latency. Deferred argmax epilogue: the operand
// re-reads for step t's backpointer (wa_buf LDS row + trans global row, both
// bitwise-identical sources) are issued at the end of step t and consumed at
// the top of step t+1 -- a full iteration of latency cover, no live c[64]
// (which spilled in R5: 2 GB scratch traffic).
//   - forward: f16 ea broadcast + v_dot2, 2-step-pipelined wave-uniform ref
//     (staleness only changes the normalizer; exact logsumexp at the end)
//   - viterbi: exact fp32 adds / commutative maxes; descending equality scans
//     give first-index tie-breaks (absmax 0.0 verified)
//   - feats prefetch ring depth 4; bp in LDS; shfl-chain backtrace
//   - gold score folded into the block prologue
// Structural floor (12-round evidence): ~250 VALU instr/step + ~28 DS ops/step
// x 4 batches/CU sharing the DS pipe + 2 LDS RTs on the serial chain all give
// ~1400-1800 cyc/step = the observed 350-400 us plateau.
// ---------------------------------------------------------------------------
__global__ __launch_bounds__(64, 1) void crf_kernel(const float* __restrict__ feats,
                                                    const int* __restrict__ tags,
                                                    const float* __restrict__ trans,
                                                    float* __restrict__ out) {
    __shared__ unsigned char bp[TT][KK];            // 32 KB backpointers
    __shared__ __align__(16) float wa_buf[KK];      // viterbi alpha broadcast
    __shared__ __align__(16) _Float16 ea_buf[KK];   // exp(alpha - ref), f16

    const int b = blockIdx.x;
    const int lane = threadIdx.x;

    // ---- gold score (one-time, lane-parallel gather) ----
    const int* tg = tags + (size_t)b * TT;
    float gold = 0.f;
#pragma unroll
    for (int i = 0; i < TT / 64; ++i) {
        int t = lane + i * 64;
        int nxt = tg[t];
        int prv = t ? tg[t - 1] : 0;
        gold += trans[nxt * KK + prv] + feats[((size_t)b * TT + t) * KK + nxt];
    }
    if (lane == 0) gold += trans[(KK - 1) * KK + tg[TT - 1]];  // STOP term
#pragma unroll
    for (int d = 1; d < 64; d <<= 1) gold += __shfl_xor(gold, d);

    // ---- per-lane transition row (lane = next state) ----
    float tr[KK];
    h2 Er_pk[KK / 2];   // exp(tr) packed f16 pairs for the forward dot2
    {
        const float4* trow = reinterpret_cast<const float4*>(trans + lane * KK);
#pragma unroll
        for (int i = 0; i < KK / 4; ++i) {
            float4 v = trow[i];
            tr[4 * i + 0] = v.x; tr[4 * i + 1] = v.y;
            tr[4 * i + 2] = v.z; tr[4 * i + 3] = v.w;
            h2 lo, hi;
            lo.x = (_Float16)__expf(v.x); lo.y = (_Float16)__expf(v.y);
            hi.x = (_Float16)__expf(v.z); hi.y = (_Float16)__expf(v.w);
            Er_pk[2 * i] = lo;
            Er_pk[2 * i + 1] = hi;
        }
    }
    const float t63 = trans[(KK - 1) * KK + lane];  // trans[STOP][lane]

    float a = (lane == 0) ? 0.f : NEGV;   // forward alpha (log domain)
    float w = a;                          // viterbi alpha (lane = state)
    wa_buf[lane] = w;
    // pipelined wave-uniform normalizer: refUse(t) = shfl(a_{t-2}, 8) + 5
    float refUse = 0.f, refMid = 6.f, refNew = 12.f;

    // feats prefetch ring, depth 4
    const float* fbp = feats + (size_t)b * TT * KK + lane;
    float f0 = fbp[0 * KK];
    float f1 = fbp[1 * KK];
    float f2 = fbp[2 * KK];
    float f3 = fbp[3 * KK];
    const float* fp = fbp + 4 * KK;

    // pending (deferred) epilogue state for step t-1
    float4 p_wa0 = {}, p_wa1 = {}, p_tg0 = {}, p_tg1 = {};
    float p_m = 0.f;
    int p_base = 0;

    for (int t = 0; t < TT; ++t) {
        // ---- finish step t-1: argmax compare + bp store (operands have had a
        //      full iteration of latency cover) ----
        if (t) {
            int bpv = p_base;
            float vv;
            vv = p_wa1.w + p_tg1.w; if (vv == p_m) bpv = p_base + 7;
            vv = p_wa1.z + p_tg1.z; if (vv == p_m) bpv = p_base + 6;
            vv = p_wa1.y + p_tg1.y; if (vv == p_m) bpv = p_base + 5;
            vv = p_wa1.x + p_tg1.x; if (vv == p_m) bpv = p_base + 4;
            vv = p_wa0.w + p_tg0.w; if (vv == p_m) bpv = p_base + 3;
            vv = p_wa0.z + p_tg0.z; if (vv == p_m) bpv = p_base + 2;
            vv = p_wa0.y + p_tg0.y; if (vv == p_m) bpv = p_base + 1;
            vv = p_wa0.x + p_tg0.x; if (vv == p_m) bpv = p_base + 0;
            bp[t - 1][lane] = (unsigned char)bpv;
        }

        const float f_cur = f0;
        f0 = f1; f1 = f2; f2 = f3;
        f3 = *fp;                       // row min(t+4, TT-1)
        if (t + 5 < TT) fp += KK;

        // ======== forward: publish normalized exp(alpha), f16 ========
        float x = fminf(a - refUse, 11.0f);     // e^11 < f16 max
        ea_buf[lane] = (_Float16)__expf(x);
        // single-wave block: in-order DS pipe, no barrier needed

        // ======== viterbi: candidates + group maxima (no c[] kept) ========
        float gm[8];
        const float4* wb = reinterpret_cast<const float4*>(wa_buf);
#pragma unroll
        for (int g = 0; g < 8; ++g) {
            float4 wA = wb[2 * g];
            float4 wB = wb[2 * g + 1];
            float c0 = wA.x + tr[8 * g + 0];
            float c1 = wA.y + tr[8 * g + 1];
            float c2 = wA.z + tr[8 * g + 2];
            float c3 = wA.w + tr[8 * g + 3];
            float c4 = wB.x + tr[8 * g + 4];
            float c5 = wB.y + tr[8 * g + 5];
            float c6 = wB.z + tr[8 * g + 6];
            float c7 = wB.w + tr[8 * g + 7];
            gm[g] = fmaxf(fmaxf(fmaxf(c0, c1), fmaxf(c2, c3)),
                          fmaxf(fmaxf(c4, c5), fmaxf(c6, c7)));
        }

        // ======== forward: dot-products over the broadcast ========
        const float4* eb = reinterpret_cast<const float4*>(ea_buf);
        float s0 = 0.f, s1 = 0.f, s2 = 0.f, s3 = 0.f;
        float s4 = 0.f, s5 = 0.f, s6 = 0.f, s7 = 0.f;
#pragma unroll
        for (int q = 0; q < 8; ++q) {
            float4 e4 = eb[q];
            float acc = 0.f;
            acc = dot2_acc(bc_h2(e4.x), Er_pk[4 * q + 0], acc);
            acc = dot2_acc(bc_h2(e4.y), Er_pk[4 * q + 1], acc);
            acc = dot2_acc(bc_h2(e4.z), Er_pk[4 * q + 2], acc);
            acc = dot2_acc(bc_h2(e4.w), Er_pk[4 * q + 3], acc);
            switch (q) {   // 8 independent chains
                case 0: s0 = acc; break; case 1: s1 = acc; break;
                case 2: s2 = acc; break; case 3: s3 = acc; break;
                case 4: s4 = acc; break; case 5: s5 = acc; break;
                case 6: s6 = acc; break; case 7: s7 = acc; break;
            }
        }
        float s = ((s0 + s1) + (s2 + s3)) + ((s4 + s5) + (s6 + s7));
        float a_new = __logf(s) + refUse + f_cur;
        refUse = refMid;
        refMid = refNew;
        refNew = __shfl(a_new, 8) + 5.0f;   // consumed 2 iterations later
        a = a_new;

        // ======== viterbi: max, group select, issue deferred loads ========
        float m = fmaxf(fmaxf(fmaxf(gm[0], gm[1]), fmaxf(gm[2], gm[3])),
                        fmaxf(fmaxf(gm[4], gm[5]), fmaxf(gm[6], gm[7])));
        int g = 0;
#pragma unroll
        for (int j = 7; j >= 0; --j)   // descending: smallest matching group
            if (gm[j] == m) g = j;
        const int base = g * 8;

        // re-reads consumed NEXT iteration; wa reads BEFORE the write (old vals)
        const float4* wam = reinterpret_cast<const float4*>(wa_buf + base);
        p_wa0 = wam[0];
        p_wa1 = wam[1];
        wa_buf[lane] = m + f_cur;           // in-order DS pipe: reads saw old
        const float4* trg = reinterpret_cast<const float4*>(trans + lane * KK + base);
        p_tg0 = trg[0];
        p_tg1 = trg[1];                     // L1/L2-resident, full-step cover
        p_m = m;
        p_base = base;
        w = m + f_cur;
    }
    // finish last step's bp
    {
        int bpv = p_base;
        float vv;
        vv = p_wa1.w + p_tg1.w; if (vv == p_m) bpv = p_base + 7;
        vv = p_wa1.z + p_tg1.z; if (vv == p_m) bpv = p_base + 6;
        vv = p_wa1.y + p_tg1.y; if (vv == p_m) bpv = p_base + 5;
        vv = p_wa1.x + p_tg1.x; if (vv == p_m) bpv = p_base + 4;
        vv = p_wa0.w + p_tg0.w; if (vv == p_m) bpv = p_base + 3;
        vv = p_wa0.z + p_tg0.z; if (vv == p_m) bpv = p_base + 2;
        vv = p_wa0.y + p_tg0.y; if (vv == p_m) bpv = p_base + 1;
        vv = p_wa0.x + p_tg0.x; if (vv == p_m) bpv = p_base + 0;
        bp[TT - 1][lane] = (unsigned char)bpv;
    }

    // ---- forward score: exact logsumexp(alpha_T + trans[STOP][:]) ----
    float v = a + t63;
    float mm = v;
#pragma unroll
    for (int d = 32; d; d >>= 1) mm = fmaxf(mm, __shfl_xor(mm, d));
    float es = __expf(v - mm);
#pragma unroll
    for (int d = 32; d; d >>= 1) es += __shfl_xor(es, d);
    float fscore = mm + __logf(es);

    // ---- viterbi terminal: max + first-index argmax (exact) ----
    float tv = w + t63;
    float bvv = tv;
    int bidx = lane;
#pragma unroll
    for (int d = 1; d < 64; d <<= 1) {
        float ov = __shfl_xor(bvv, d);
        int oi = __shfl_xor(bidx, d);
        bool take = (ov > bvv) || (ov == bvv && oi < bidx);
        bvv = take ? ov : bvv;
        bidx = take ? oi : bidx;
    }

    if (lane == 0) {
        out[b] = fscore - gold;
        out[BB + b] = bvv;
    }

    // ---- backtrace: bulk LDS row loads + dynamic-shfl chain ----
    float* outp = out + 2 * BB + (size_t)b * TT;
    int cur = bidx;                 // wave-uniform
    float my = 0.f;                 // latched path values (lane = t & 63)
    for (int tb = TT - 16; tb >= 0; tb -= 16) {
        int r[16];
#pragma unroll
        for (int j = 0; j < 16; ++j) r[j] = bp[tb + j][lane];
#pragma unroll
        for (int j = 15; j >= 0; --j) {
            my = (lane == ((tb + j) & 63)) ? (float)cur : my;
            cur = __shfl(r[j], cur);
        }
        if ((tb & 63) == 0) outp[tb + lane] = my;   // coalesced 64-wide store
    }
}

extern "C" void kernel_launch(void* const* d_in, const int* in_sizes, int n_in,
                              void* d_out, int out_size, void* d_ws, size_t ws_size,
                              hipStream_t stream) {
    const float* feats = (const float*)d_in[0];
    const int* tags = (const int*)d_in[1];
    const float* trans = (const float*)d_in[2];
    float* out = (float*)d_out;

    crf_kernel<<<BB, 64, 0, stream>>>(feats, tags, trans, out);
}